// Round 13
// baseline (242.659 us; speedup 1.0000x reference)
//
#include <hip/hip_runtime.h>
#include <hip/hip_bf16.h>
#include <cstddef>

#define B_   8
#define C_   256
#define HH   64
#define WW   64
#define NPOS 4096
#define NH   8
#define HD   32
#define NA   16
#define NHA  128      // NH*NA
#define SCALE 0.17677669529663687f

typedef unsigned short u16;
typedef __attribute__((ext_vector_type(8))) short bf16x8;
typedef __attribute__((ext_vector_type(4))) float f32x4;

__device__ __forceinline__ float bfbits2f(u16 u) {
  union { unsigned int i; float f; } x; x.i = ((unsigned int)u) << 16; return x.f;
}
__device__ __forceinline__ u16 f2bfbits(float f) {
  union { float f; unsigned int i; } x; x.f = f;
  unsigned int r = x.i + 0x7fffu + ((x.i >> 16) & 1u);
  return (u16)(r >> 16);
}
__device__ __forceinline__ void unpack8(const uint4 v, float* f) {
  f[0] = bfbits2f((u16)(v.x & 0xffff)); f[1] = bfbits2f((u16)(v.x >> 16));
  f[2] = bfbits2f((u16)(v.y & 0xffff)); f[3] = bfbits2f((u16)(v.y >> 16));
  f[4] = bfbits2f((u16)(v.z & 0xffff)); f[5] = bfbits2f((u16)(v.z >> 16));
  f[6] = bfbits2f((u16)(v.w & 0xffff)); f[7] = bfbits2f((u16)(v.w >> 16));
}

// ---------------- w~ = SCALE*(W_K agent) + kvb-dot + qd, with inline agent pooling ----------------
__global__ __launch_bounds__(256) void k_wtilde(const u16* __restrict__ Wkt, const float* __restrict__ kv_b,
                                                const float* __restrict__ g,
                                                const float* __restrict__ q_w, const float* __restrict__ q_b,
                                                u16* __restrict__ wt, float* __restrict__ kvbD,
                                                float* __restrict__ qd) {
  const int h = blockIdx.x, b = blockIdx.y;
  const int t = threadIdx.x;
  __shared__ u16 Wk[32 * 256];
  __shared__ float ags[16][32];
  __shared__ float red[256];
  __shared__ float gb[16];
  {
    const int ag = t >> 4, sub = t & 15;
    const int p1 = ag >> 2, p2 = ag & 3;
    const int yy = p1 * 16 + sub, xx0 = p2 * 16;
    const float* gp = g + (size_t)b * NPOS + yy * WW + xx0;
    float s = 0.f;
#pragma unroll
    for (int i = 0; i < 16; ++i) s += gp[i];
    red[t] = s;
  }
#pragma unroll
  for (int i = 0; i < 4; ++i) {
    const int idx = t + 256 * i;
    const int r = idx >> 5, sl = idx & 31;
    *(uint4*)(Wk + r * 256 + sl * 8) = *(const uint4*)(Wkt + (size_t)(h * 32 + r) * C_ + sl * 8);
  }
  __syncthreads();
  if ((t & 15) == 0) {
    const int ag = t >> 4;
    float tot = 0.f;
#pragma unroll
    for (int i = 0; i < 16; ++i) tot += red[(ag << 4) + i];
    gb[ag] = tot * (1.0f / 256.0f);
  }
  __syncthreads();
#pragma unroll
  for (int i = 0; i < 2; ++i) {
    const int idx = t + 256 * i;
    const int a = idx >> 5, d = idx & 31;
    ags[a][d] = (gb[a] * q_w[h * HD + d] + q_b[h * HD + d]) * SCALE;
  }
  __syncthreads();
  const int a = t >> 4, cb = (t & 15) * 16;
  float o[16];
#pragma unroll
  for (int k = 0; k < 16; ++k) o[k] = 0.f;
  for (int d = 0; d < 32; ++d) {
    const float av = ags[a][d];
#pragma unroll
    for (int k = 0; k < 16; ++k) o[k] += av * bfbits2f(Wk[d * 256 + cb + k]);
  }
  unsigned int w[8];
#pragma unroll
  for (int q = 0; q < 8; ++q)
    w[q] = (unsigned int)f2bfbits(o[2 * q]) | ((unsigned int)f2bfbits(o[2 * q + 1]) << 16);
  u16* op = wt + ((size_t)(b * NHA + h * 16 + a)) * C_ + cb;
  *(uint4*)op = make_uint4(w[0], w[1], w[2], w[3]);
  *(uint4*)(op + 8) = make_uint4(w[4], w[5], w[6], w[7]);
  if ((t & 15) == 0) {
    float s = 0.f;
#pragma unroll
    for (int d = 0; d < 32; ++d) s += ags[a][d] * kv_b[h * 32 + d];
    kvbD[b * NHA + h * 16 + a] = s;
  }
  if ((t & 15) == 1) {
    float s1 = 0.f, s2 = 0.f;
#pragma unroll
    for (int d = 0; d < 32; ++d) {
      s1 += ags[a][d] * q_w[h * HD + d];
      s2 += ags[a][d] * q_b[h * HD + d];
    }
    qd[(size_t)b * 256 + h * 32 + a * 2 + 0] = s1;
    qd[(size_t)b * 256 + h * 32 + a * 2 + 1] = s2;
  }
}

// ---------------- biases: posbT (pos, ha) f32 only ----------------
__global__ __launch_bounds__(256) void k_bias(const float* __restrict__ an_b,
                                              const float* __restrict__ ah_b, const float* __restrict__ aw_b,
                                              float* __restrict__ posbT) {
  const int idx = blockIdx.x * 256 + threadIdx.x;
  const int ha = idx & 127;
  const int pos = idx >> 7;
  const int h = ha >> 4, a = ha & 15;
  const int y = pos >> 6, x = pos & 63;
  const float sy = (y + 0.5f) * 0.0625f - 0.5f;
  const float sx = (x + 0.5f) * 0.0625f - 0.5f;
  const int y0 = (int)floorf(sy);
  const int x0 = (int)floorf(sx);
  const float wy = sy - (float)y0, wx = sx - (float)x0;
  const int y0c = min(max(y0, 0), 3), y1c = min(max(y0 + 1, 0), 3);
  const int x0c = min(max(x0, 0), 3), x1c = min(max(x0 + 1, 0), 3);
  const float* an4 = an_b + ((size_t)h * NA + a) * 16;
  const float pa_ = (1.f - wy) * ((1.f - wx) * an4[y0c * 4 + x0c] + wx * an4[y0c * 4 + x1c]) +
                    wy * ((1.f - wx) * an4[y1c * 4 + x0c] + wx * an4[y1c * 4 + x1c]);
  posbT[(size_t)pos * NHA + ha] = pa_ + ah_b[((size_t)h * NA + a) * HH + y] + aw_b[((size_t)h * NA + a) * WW + x];
}

// ---------------- transpose+convert inputs: in (b,c,n) f32 -> At (b,n,c) bf16 ----------------
__global__ __launch_bounds__(256) void k_prep_in(const float* __restrict__ in1, const float* __restrict__ in2,
                                                 u16* __restrict__ At1, u16* __restrict__ At2) {
  const int z = blockIdx.z;
  const int src = z >> 3, b = z & 7;
  const float* in = src ? in2 : in1;
  u16* At = src ? At2 : At1;
  const int pos0 = blockIdx.x * 64;
  const int ci0 = blockIdx.y * 64;
  __shared__ float tile[64][68];
  const int t = threadIdx.x;
  const int rpos = (t & 15) << 2, rci = t >> 4;
#pragma unroll
  for (int i = 0; i < 4; ++i) {
    const int ci_l = rci + 16 * i;
    const float4 v = *(const float4*)(in + ((size_t)b * C_ + ci0 + ci_l) * NPOS + pos0 + rpos);
    tile[ci_l][rpos + 0] = v.x; tile[ci_l][rpos + 1] = v.y;
    tile[ci_l][rpos + 2] = v.z; tile[ci_l][rpos + 3] = v.w;
  }
  __syncthreads();
#pragma unroll
  for (int i = 0; i < 2; ++i) {
    const int u = t + 256 * i;
    const int p = u >> 3, s = u & 7;
    unsigned int w[4];
#pragma unroll
    for (int q = 0; q < 4; ++q) {
      const u16 lo = f2bfbits(tile[s * 8 + 2 * q][p]);
      const u16 hi = f2bfbits(tile[s * 8 + 2 * q + 1][p]);
      w[q] = (unsigned int)lo | ((unsigned int)hi << 16);
    }
    *(uint4*)(At + ((size_t)(pos0 + p)) * C_ + (size_t)b * NPOS * C_ + ci0 + s * 8) =
        make_uint4(w[0], w[1], w[2], w[3]);
  }
}

// ---------------- transpose+convert weights (+ dwconv table as block 48) ----------------
__global__ __launch_bounds__(256) void k_prep_w(const float* __restrict__ kv_w, const float* __restrict__ proj_w,
                                                const float* __restrict__ dwc_w, const float* __restrict__ dwc_b,
                                                u16* __restrict__ Wkt, u16* __restrict__ Pwt,
                                                float* __restrict__ dwcT) {
  const int x = blockIdx.x;
  const int t = threadIdx.x;
  if (x == 48) {
    const int ci = t;
#pragma unroll
    for (int q = 0; q < 9; ++q) dwcT[q * 256 + ci] = dwc_w[ci * 9 + q];
    dwcT[9 * 256 + ci] = dwc_b[ci];
    return;
  }
  const float* W; u16* T; int j0, ci0, ncols;
  if (x < 32) { W = kv_w;  T = Wkt; j0 = (x & 7) * 64; ci0 = (x >> 3) * 64; ncols = 512; }
  else        { W = proj_w; T = Pwt; j0 = ((x - 32) & 3) * 64; ci0 = ((x - 32) >> 2) * 64; ncols = 256; }
  __shared__ float tile[64][68];
  const int rj = (t & 15) << 2, rci = t >> 4;
#pragma unroll
  for (int i = 0; i < 4; ++i) {
    const int ci_l = rci + 16 * i;
    const float4 v = *(const float4*)(W + (size_t)(ci0 + ci_l) * ncols + j0 + rj);
    tile[ci_l][rj + 0] = v.x; tile[ci_l][rj + 1] = v.y;
    tile[ci_l][rj + 2] = v.z; tile[ci_l][rj + 3] = v.w;
  }
  __syncthreads();
#pragma unroll
  for (int i = 0; i < 2; ++i) {
    const int u = t + 256 * i;
    const int p = u >> 3, s = u & 7;
    unsigned int w[4];
#pragma unroll
    for (int q = 0; q < 4; ++q) {
      const u16 lo = f2bfbits(tile[s * 8 + 2 * q][p]);
      const u16 hi = f2bfbits(tile[s * 8 + 2 * q + 1][p]);
      w[q] = (unsigned int)lo | ((unsigned int)hi << 16);
    }
    *(uint4*)(T + (size_t)(j0 + p) * C_ + ci0 + s * 8) = make_uint4(w[0], w[1], w[2], w[3]);
  }
}

// ---------------- V projection only: V[b,pos,256] = At @ Wv + bv ----------------
__global__ __launch_bounds__(256) void k_v_mfma(const u16* __restrict__ At1, const u16* __restrict__ At2,
                                                const u16* __restrict__ Wkt, const float* __restrict__ kv_b,
                                                u16* __restrict__ v1, u16* __restrict__ v2) {
  const int z = blockIdx.z;
  const int src = z >> 3, b = z & 7;
  const u16* At = src ? At2 : At1;
  u16* vout = src ? v2 : v1;
  const int pos0 = blockIdx.x * 128;
  const int j0 = blockIdx.y * 128;

  __shared__ __align__(16) u16 SM[16384];
  u16* Ab = SM;
  u16* Bb = SM + 8192;

  const int t = threadIdx.x;
  const int wave = t >> 6, lane = t & 63;
  const int wm = wave >> 1, wn = wave & 1;
  const int g = lane >> 4;

  const u16* Ag = Wkt + (size_t)(256 + j0) * C_;
  const u16* Bg = At + ((size_t)b * NPOS + pos0) * C_;

  f32x4 acc[4][4];
#pragma unroll
  for (int m = 0; m < 4; ++m)
#pragma unroll
    for (int n = 0; n < 4; ++n) { acc[m][n][0]=0.f; acc[m][n][1]=0.f; acc[m][n][2]=0.f; acc[m][n][3]=0.f; }

  uint4 ra[4], rb[4];
#define V_LOAD(KT)                                                         \
  _Pragma("unroll") for (int i = 0; i < 4; ++i) {                          \
    const int u = t + 256 * i, rr = u >> 3, ss = u & 7;                    \
    ra[i] = *(const uint4*)(Ag + (size_t)rr * C_ + (KT) * 64 + ss * 8);    \
    rb[i] = *(const uint4*)(Bg + (size_t)rr * C_ + (KT) * 64 + ss * 8);    \
  }
#define V_WRITE()                                                          \
  _Pragma("unroll") for (int i = 0; i < 4; ++i) {                          \
    const int u = t + 256 * i, rr = u >> 3, ss = u & 7;                    \
    const int sw = ((ss ^ (rr & 7)) << 3);                                 \
    *(uint4*)(Ab + rr * 64 + sw) = ra[i];                                  \
    *(uint4*)(Bb + rr * 64 + sw) = rb[i];                                  \
  }

  V_LOAD(0);
  V_WRITE();
  V_LOAD(1);
  __syncthreads();

  for (int kt = 0; kt < 4; ++kt) {
#pragma unroll
    for (int kk = 0; kk < 2; ++kk) {
      bf16x8 af[4], bfr[4];
#pragma unroll
      for (int m = 0; m < 4; ++m) {
        const int r = wm * 64 + m * 16 + (lane & 15);
        af[m] = *(const bf16x8*)(Ab + r * 64 + (((kk * 4 + g) ^ (r & 7)) << 3));
      }
#pragma unroll
      for (int n = 0; n < 4; ++n) {
        const int c = wn * 64 + n * 16 + (lane & 15);
        bfr[n] = *(const bf16x8*)(Bb + c * 64 + (((kk * 4 + g) ^ (c & 7)) << 3));
      }
#pragma unroll
      for (int m = 0; m < 4; ++m)
#pragma unroll
        for (int n = 0; n < 4; ++n)
          acc[m][n] = __builtin_amdgcn_mfma_f32_16x16x32_bf16(af[m], bfr[n], acc[m][n], 0, 0, 0);
    }
    if (kt < 3) {
      __syncthreads();
      V_WRITE();
      if (kt < 2) V_LOAD(kt + 2);
      __syncthreads();
    }
  }
#undef V_LOAD
#undef V_WRITE

  __syncthreads();
#pragma unroll
  for (int m = 0; m < 4; ++m) {
    const int jl = wm * 64 + m * 16 + (lane >> 4) * 4;
    const float4 bv = *(const float4*)(kv_b + 256 + j0 + jl);
#pragma unroll
    for (int n = 0; n < 4; ++n) {
      const int pos_l = wn * 64 + n * 16 + (lane & 15);
      const f32x4 a = acc[m][n];
      ushort4 st;
      st.x = f2bfbits(a[0] + bv.x); st.y = f2bfbits(a[1] + bv.y);
      st.z = f2bfbits(a[2] + bv.z); st.w = f2bfbits(a[3] + bv.w);
      const int slot = (jl >> 3) ^ (pos_l & 7);
      *(ushort4*)(SM + pos_l * 128 + slot * 8 + (jl & 7)) = st;
    }
  }
  __syncthreads();
#pragma unroll
  for (int i = 0; i < 8; ++i) {
    const int idx = t + 256 * i;
    const int row = idx >> 4, sl = idx & 15;
    const uint4 v = *(const uint4*)(SM + row * 128 + ((sl ^ (row & 7)) << 3));
    *(uint4*)(vout + ((size_t)b * NPOS + pos0 + row) * C_ + j0 + sl * 8) = v;
  }
}

// ---------------- score GEMM: E[sb,ha,pos] = exp(At @ wt^T + posbT + kvbD) bf16, + row sums ----------------
__global__ __launch_bounds__(256) void k_score(const u16* __restrict__ At1, const u16* __restrict__ At2,
                                               const u16* __restrict__ wt, const float* __restrict__ posbT,
                                               const float* __restrict__ kvbD,
                                               u16* __restrict__ E, float* __restrict__ lsumP) {
  const int z = blockIdx.z;
  const int src = z >> 3, b = z & 7;
  const int sb = src * 8 + b;
  const u16* At = src ? At2 : At1;
  const int pos0 = blockIdx.x * 128;

  __shared__ __align__(16) u16 SM[16384];
  __shared__ float lsum_sm[2][128];
  u16* Ab = SM;
  u16* Bb = SM + 8192;

  const int t = threadIdx.x;
  const int wave = t >> 6, lane = t & 63;
  const int wm = wave >> 1, wn = wave & 1;
  const int g = lane >> 4;

  const u16* Ag = At + ((size_t)b * NPOS + pos0) * C_;
  const u16* Bg = wt + (size_t)b * NHA * C_;

  f32x4 acc[4][4];
#pragma unroll
  for (int m = 0; m < 4; ++m)
#pragma unroll
    for (int n = 0; n < 4; ++n) { acc[m][n][0]=0.f; acc[m][n][1]=0.f; acc[m][n][2]=0.f; acc[m][n][3]=0.f; }

  uint4 ra[4], rb[4];
#define S_LOAD(KT)                                                         \
  _Pragma("unroll") for (int i = 0; i < 4; ++i) {                          \
    const int u = t + 256 * i, rr = u >> 3, ss = u & 7;                    \
    ra[i] = *(const uint4*)(Ag + (size_t)rr * C_ + (KT) * 64 + ss * 8);    \
    rb[i] = *(const uint4*)(Bg + (size_t)rr * C_ + (KT) * 64 + ss * 8);    \
  }
#define S_WRITE()                                                          \
  _Pragma("unroll") for (int i = 0; i < 4; ++i) {                          \
    const int u = t + 256 * i, rr = u >> 3, ss = u & 7;                    \
    const int sw = ((ss ^ (rr & 7)) << 3);                                 \
    *(uint4*)(Ab + rr * 64 + sw) = ra[i];                                  \
    *(uint4*)(Bb + rr * 64 + sw) = rb[i];                                  \
  }

  S_LOAD(0);
  S_WRITE();
  S_LOAD(1);
  __syncthreads();

  for (int kt = 0; kt < 4; ++kt) {
#pragma unroll
    for (int kk = 0; kk < 2; ++kk) {
      bf16x8 af[4], bfr[4];
#pragma unroll
      for (int m = 0; m < 4; ++m) {
        const int r = wm * 64 + m * 16 + (lane & 15);
        af[m] = *(const bf16x8*)(Ab + r * 64 + (((kk * 4 + g) ^ (r & 7)) << 3));
      }
#pragma unroll
      for (int n = 0; n < 4; ++n) {
        const int c = wn * 64 + n * 16 + (lane & 15);
        bfr[n] = *(const bf16x8*)(Bb + c * 64 + (((kk * 4 + g) ^ (c & 7)) << 3));
      }
#pragma unroll
      for (int m = 0; m < 4; ++m)
#pragma unroll
        for (int n = 0; n < 4; ++n)
          acc[m][n] = __builtin_amdgcn_mfma_f32_16x16x32_bf16(af[m], bfr[n], acc[m][n], 0, 0, 0);
    }
    if (kt < 3) {
      __syncthreads();
      S_WRITE();
      if (kt < 2) S_LOAD(kt + 2);
      __syncthreads();
    }
  }
#undef S_LOAD
#undef S_WRITE

  __syncthreads();
  float ls[4] = {0.f, 0.f, 0.f, 0.f};
#pragma unroll
  for (int n = 0; n < 4; ++n) {
    const int ha_l = wn * 64 + n * 16 + (lane & 15);
    const float kb = kvbD[b * NHA + ha_l];
#pragma unroll
    for (int m = 0; m < 4; ++m) {
      const int pos_l = wm * 64 + m * 16 + (lane >> 4) * 4;
      float e[4];
#pragma unroll
      for (int j = 0; j < 4; ++j) {
        const float s = acc[m][n][j] + posbT[(size_t)(pos0 + pos_l + j) * NHA + ha_l] + kb;
        e[j] = __expf(s);
        ls[n] += e[j];
      }
      ushort4 st;
      st.x = f2bfbits(e[0]); st.y = f2bfbits(e[1]); st.z = f2bfbits(e[2]); st.w = f2bfbits(e[3]);
      const int sw = (pos_l >> 3) ^ (ha_l & 15);
      *(ushort4*)(SM + ha_l * 128 + sw * 8 + (pos_l & 7)) = st;
    }
  }
#pragma unroll
  for (int n = 0; n < 4; ++n) {
    float v = ls[n];
    v += __shfl_xor(v, 16);
    v += __shfl_xor(v, 32);
    ls[n] = v;
  }
  if (lane < 16) {
#pragma unroll
    for (int n = 0; n < 4; ++n) lsum_sm[wm][wn * 64 + n * 16 + lane] = ls[n];
  }
  __syncthreads();
  if (t < 128)
    lsumP[((size_t)sb * 32 + blockIdx.x) * NHA + t] = lsum_sm[0][t] + lsum_sm[1][t];
#pragma unroll
  for (int i = 0; i < 8; ++i) {
    const int idx = t + 256 * i;
    const int row = idx >> 4, sl = idx & 15;
    const uint4 v = *(const uint4*)(SM + row * 128 + ((sl ^ (row & 15)) << 3));
    *(uint4*)(E + ((size_t)sb * NHA + row) * NPOS + pos0 + sl * 8) = v;
  }
}

// ---------------- PV GEMM: T_p[sb,kc,ha,ci] = sum_pos in[ci,pos] * E[ha,pos] ----------------
__global__ __launch_bounds__(256) void k_pv(const float* __restrict__ in1, const float* __restrict__ in2,
                                            const u16* __restrict__ E, float* __restrict__ T_p) {
  const int kc = blockIdx.x;
  const int ci0 = blockIdx.y * 128;
  const int sb = blockIdx.z;
  const int src = sb >> 3, b = sb & 7;
  const float* in = src ? in2 : in1;
  const int kpos0 = kc * 512;

  __shared__ __align__(16) u16 As[8192];
  __shared__ __align__(16) u16 Bs[8192];

  const int t = threadIdx.x;
  const int wave = t >> 6, lane = t & 63;
  const int wm = wave >> 1, wn = wave & 1;
  const int g = lane >> 4;

  const float* Ain = in + (size_t)b * C_ * NPOS;
  const u16* Eg = E + (size_t)sb * NHA * NPOS;

  f32x4 acc[4][4];
#pragma unroll
  for (int m = 0; m < 4; ++m)
#pragma unroll
    for (int n = 0; n < 4; ++n) { acc[m][n][0]=0.f; acc[m][n][1]=0.f; acc[m][n][2]=0.f; acc[m][n][3]=0.f; }

  float4 pa[8];
  uint4 pb[4];
#define PV_LOAD(KT)                                                            \
  _Pragma("unroll") for (int i = 0; i < 8; ++i) {                              \
    const int idx = t + 256 * i, rr = idx >> 4, fq = idx & 15;                 \
    pa[i] = *(const float4*)(Ain + (size_t)(ci0 + rr) * NPOS + kpos0 + (KT) * 64 + fq * 4); \
  }                                                                            \
  _Pragma("unroll") for (int i = 0; i < 4; ++i) {                              \
    const int idx = t + 256 * i, rr = idx >> 3, ss = idx & 7;                  \
    pb[i] = *(const uint4*)(Eg + (size_t)rr * NPOS + kpos0 + (KT) * 64 + ss * 8); \
  }
#define PV_WRITE()                                                             \
  _Pragma("unroll") for (int i = 0; i < 8; ++i) {                              \
    const int idx = t + 256 * i, rr = idx >> 4, fq = idx & 15;                 \
    ushort4 st;                                                                \
    st.x = f2bfbits(pa[i].x); st.y = f2bfbits(pa[i].y);                        \
    st.z = f2bfbits(pa[i].z); st.w = f2bfbits(pa[i].w);                        \
    const int sw = ((fq >> 1) ^ (rr & 7));                                     \
    *(ushort4*)(As + rr * 64 + sw * 8 + (fq & 1) * 4) = st;                    \
  }                                                                            \
  _Pragma("unroll") for (int i = 0; i < 4; ++i) {                              \
    const int idx = t + 256 * i, rr = idx >> 3, ss = idx & 7;                  \
    *(uint4*)(Bs + rr * 64 + ((ss ^ (rr & 7)) << 3)) = pb[i];                  \
  }

  PV_LOAD(0);
  PV_WRITE();
  PV_LOAD(1);
  __syncthreads();

  for (int kt = 0; kt < 8; ++kt) {
#pragma unroll
    for (int kk = 0; kk < 2; ++kk) {
      bf16x8 af[4], bfr[4];
#pragma unroll
      for (int m = 0; m < 4; ++m) {
        const int r = wm * 64 + m * 16 + (lane & 15);
        af[m] = *(const bf16x8*)(As + r * 64 + (((kk * 4 + g) ^ (r & 7)) << 3));
      }
#pragma unroll
      for (int n = 0; n < 4; ++n) {
        const int c = wn * 64 + n * 16 + (lane & 15);
        bfr[n] = *(const bf16x8*)(Bs + c * 64 + (((kk * 4 + g) ^ (c & 7)) << 3));
      }
#pragma unroll
      for (int m = 0; m < 4; ++m)
#pragma unroll
        for (int n = 0; n < 4; ++n)
          acc[m][n] = __builtin_amdgcn_mfma_f32_16x16x32_bf16(af[m], bfr[n], acc[m][n], 0, 0, 0);
    }
    if (kt < 7) {
      __syncthreads();
      PV_WRITE();
      if (kt < 6) PV_LOAD(kt + 2);
      __syncthreads();
    }
  }
#undef PV_LOAD
#undef PV_WRITE

#pragma unroll
  for (int m = 0; m < 4; ++m) {
    const int ci_l = wm * 64 + m * 16 + (lane >> 4) * 4;
#pragma unroll
    for (int n = 0; n < 4; ++n) {
      const int ha_l = wn * 64 + n * 16 + (lane & 15);
      const f32x4 a = acc[m][n];
      *(float4*)(T_p + (((size_t)sb * 8 + kc) * NHA + ha_l) * C_ + ci0 + ci_l) =
          make_float4(a[0], a[1], a[2], a[3]);
    }
  }
}

// ---------------- agent_v = (sum_kc T)/lsum @ Wv + bv ----------------
__global__ __launch_bounds__(256) void k_agentv(const float* __restrict__ T_p, const float* __restrict__ lsumP,
                                                const u16* __restrict__ Wkt, const float* __restrict__ kv_b,
                                                float* __restrict__ agent_v) {
  const int h = blockIdx.x, sb = blockIdx.y;
  const int t = threadIdx.x;
  __shared__ float Tred[16 * 256];
  __shared__ u16 Wv[32 * 256];
  __shared__ float lsum_s[16];
#pragma unroll
  for (int i = 0; i < 4; ++i) {
    const int idx = t + 256 * i;
    const int r = idx >> 5, sl = idx & 31;
    *(uint4*)(Wv + r * 256 + sl * 8) = *(const uint4*)(Wkt + (size_t)(256 + h * 32 + r) * C_ + sl * 8);
  }
#pragma unroll
  for (int i = 0; i < 16; ++i) {
    const int idx = t + 256 * i;
    const int a = idx >> 8, ci = idx & 255;
    float s = 0.f;
#pragma unroll
    for (int kc = 0; kc < 8; ++kc)
      s += T_p[(((size_t)sb * 8 + kc) * NHA + h * 16 + a) * C_ + ci];
    Tred[a * 256 + ci] = s;
  }
  if (t < 16) {
    float s = 0.f;
#pragma unroll
    for (int pt = 0; pt < 32; ++pt) s += lsumP[((size_t)sb * 32 + pt) * NHA + h * 16 + t];
    lsum_s[t] = s;
  }
  __syncthreads();
  const int a = t >> 4, dp = (t & 15) * 2;
  float o0 = 0.f, o1 = 0.f;
  const float* Tr = Tred + a * 256;
  for (int ci = 0; ci < 256; ++ci) {
    const float tv = Tr[ci];
    o0 += tv * bfbits2f(Wv[dp * 256 + ci]);
    o1 += tv * bfbits2f(Wv[(dp + 1) * 256 + ci]);
  }
  const float inv = 1.0f / lsum_s[a];
  float* op = agent_v + (size_t)sb * NHA * HD + (h * 16 + a) * HD + dp;
  op[0] = o0 * inv + kv_b[256 + h * 32 + dp];
  op[1] = o1 * inv + kv_b[256 + h * 32 + dp + 1];
}

// ---------------- query attention: one src per block, inline agent-bias ----------------
__global__ __launch_bounds__(256) void k_qattn(const float* __restrict__ g,
                                               const float* __restrict__ qd,
                                               const float* __restrict__ agent_v,
                                               const float* __restrict__ na_b,
                                               const float* __restrict__ ha_b,
                                               const float* __restrict__ wa_b,
                                               u16* __restrict__ o1s, u16* __restrict__ o2s) {
  const int h = blockIdx.y;
  const int sb = blockIdx.z;
  const int src = sb >> 3, b = sb & 7;
  u16* out = src ? o2s : o1s;
  const int t = threadIdx.x;
  const int pos = blockIdx.x * 256 + t;
  __shared__ float dotW[16], dotB[16];
  __shared__ float av[16][32];
  __shared__ float nab[16][16];
  for (int idx = t; idx < 512; idx += 256) {
    const int a = idx >> 5, d = idx & 31;
    av[a][d] = agent_v[(size_t)sb * NHA * HD + (h * 16 + a) * HD + d];
  }
  if (t < 256 && t < 16 * 16) {
    const int a = t >> 4, q = t & 15;
    nab[a][q] = na_b[((size_t)h * NA + a) * 16 + q];
  }
  if (t < 16) {
    dotW[t] = qd[(size_t)b * 256 + h * 32 + t * 2 + 0];
    dotB[t] = qd[(size_t)b * 256 + h * 32 + t * 2 + 1];
  }
  __syncthreads();
  const int y = pos >> 6, x = pos & 63;
  const float sy = (y + 0.5f) * 0.0625f - 0.5f;
  const float sx = (x + 0.5f) * 0.0625f - 0.5f;
  const int y0 = (int)floorf(sy);
  const int x0 = (int)floorf(sx);
  const float wy = sy - (float)y0, wx = sx - (float)x0;
  const int y0c = min(max(y0, 0), 3), y1c = min(max(y0 + 1, 0), 3);
  const int x0c = min(max(x0, 0), 3), x1c = min(max(x0 + 1, 0), 3);
  const float c00 = (1.f - wy) * (1.f - wx), c01 = (1.f - wy) * wx;
  const float c10 = wy * (1.f - wx), c11 = wy * wx;
  const int i00 = y0c * 4 + x0c, i01 = y0c * 4 + x1c;
  const int i10 = y1c * 4 + x0c, i11 = y1c * 4 + x1c;
  const float* hp = ha_b + ((size_t)h * HH + y) * NA;
  const float* wp = wa_b + ((size_t)h * WW + x) * NA;
  const float gv = g[(size_t)b * NPOS + pos];
  float s[16];
  float m = -1e30f;
#pragma unroll
  for (int a = 0; a < 16; ++a) {
    const float nv = c00 * nab[a][i00] + c01 * nab[a][i01] + c10 * nab[a][i10] + c11 * nab[a][i11];
    s[a] = gv * dotW[a] + dotB[a] + nv + hp[a] + wp[a];
    m = fmaxf(m, s[a]);
  }
  float l = 0.f;
#pragma unroll
  for (int a = 0; a < 16; ++a) {
    s[a] = __expf(s[a] - m);
    l += s[a];
  }
  const float inv = 1.0f / l;
  float o[32] = {};
#pragma unroll
  for (int a = 0; a < 16; ++a) {
    const float pa = s[a] * inv;
#pragma unroll
    for (int q = 0; q < 8; ++q) {
      const float4 v4 = *(const float4*)&av[a][q * 4];
      o[q * 4 + 0] += pa * v4.x; o[q * 4 + 1] += pa * v4.y;
      o[q * 4 + 2] += pa * v4.z; o[q * 4 + 3] += pa * v4.w;
    }
  }
  u16* op = out + ((size_t)b * NPOS + pos) * C_ + h * HD;
#pragma unroll
  for (int blk = 0; blk < 4; ++blk) {
    unsigned int w1[4];
#pragma unroll
    for (int q = 0; q < 4; ++q)
      w1[q] = (unsigned int)f2bfbits(o[blk * 8 + 2 * q]) | ((unsigned int)f2bfbits(o[blk * 8 + 2 * q + 1]) << 16);
    *(uint4*)(op + blk * 8) = make_uint4(w1[0], w1[1], w1[2], w1[3]);
  }
}

// ---------------- depthwise 3x3 conv: 8ch/thread vectorized, RMW o1s/o2s ----------------
__global__ __launch_bounds__(256) void k_dwconv(const u16* __restrict__ v1, const u16* __restrict__ v2,
                                                const float* __restrict__ dwcT,
                                                u16* __restrict__ o1s, u16* __restrict__ o2s) {
  const u16* V = blockIdx.z ? v2 : v1;
  u16* out = blockIdx.z ? o2s : o1s;
  const int b = blockIdx.y;
  const int t = threadIdx.x;
  const int cg = t & 31;
  const int ch = cg * 8;
  const int px = t >> 5;
  const int pos = (blockIdx.x << 3) + px;
  const int y = pos >> 6, x = pos & 63;

  float acc[8];
  {
    const float4 b0 = *(const float4*)(dwcT + 9 * 256 + ch);
    const float4 b1 = *(const float4*)(dwcT + 9 * 256 + ch + 4);
    acc[0] = b0.x; acc[1] = b0.y; acc[2] = b0.z; acc[3] = b0.w;
    acc[4] = b1.x; acc[5] = b1.y; acc[6] = b1.z; acc[7] = b1.w;
  }
  const u16* vb = V + (size_t)b * NPOS * C_ + ch;
#pragma unroll
  for (int dy = -1; dy <= 1; ++dy) {
    const int yy = y + dy;
    if (yy < 0 || yy > 63) continue;
#pragma unroll
    for (int dx = -1; dx <= 1; ++dx) {
      const int xx = x + dx;
      if (xx < 0 || xx > 63) continue;
      const int q = (dy + 1) * 3 + (dx + 1);
      const float4 w0 = *(const float4*)(dwcT + q * 256 + ch);
      const float4 w1 = *(const float4*)(dwcT + q * 256 + ch + 4);
      const uint4 vv = *(const uint4*)(vb + (size_t)(yy * 64 + xx) * C_);
      float f8[8];
      unpack8(vv, f8);
      acc[0] += w0.x * f8[0]; acc[1] += w0.y * f8[1];
      acc[2] += w0.z * f8[2]; acc[3] += w0.w * f8[3];
      acc[4] += w1.x * f8[4]; acc[5] += w1.y * f8[5];
      acc[6] += w1.z * f8[6]; acc[7] += w1.w * f8[7];
    }
  }
  u16* op = out + ((size_t)b * NPOS + pos) * C_ + ch;
  const uint4 ov = *(const uint4*)op;
  float f8[8];
  unpack8(ov, f8);
  unsigned int wo[4];
#pragma unroll
  for (int q2 = 0; q2 < 4; ++q2)
    wo[q2] = (unsigned int)f2bfbits(f8[2 * q2] + acc[2 * q2]) |
             ((unsigned int)f2bfbits(f8[2 * q2 + 1] + acc[2 * q2 + 1]) << 16);
  *(uint4*)op = make_uint4(wo[0], wo[1], wo[2], wo[3]);
}

// ---------------- output projection, bf16 MFMA + early residual prefetch ----------------
__global__ __launch_bounds__(256) void k_proj_mfma(const u16* __restrict__ o1s, const u16* __restrict__ o2s,
                                                   const u16* __restrict__ Pwt, const float* __restrict__ proj_b,
                                                   const float* __restrict__ in1, const float* __restrict__ in2,
                                                   float* __restrict__ out1, float* __restrict__ out2) {
  const int z = blockIdx.z;
  const int src = z >> 3, b = z & 7;
  const u16* S = src ? o2s : o1s;
  const float* inp = src ? in2 : in1;
  float* outp = src ? out2 : out1;
  const int pos0 = blockIdx.x * 128;
  const int co0 = blockIdx.y * 128;

  __shared__ __align__(16) u16 SM[16384];
  u16* Ab = SM;
  u16* Bb = SM + 8192;
  float* SMF = (float*)SM;

  const int t = threadIdx.x;
  const int wave = t >> 6, lane = t & 63;
  const int wm = wave >> 1, wn = wave & 1;
  const int g = lane >> 4;

  const u16* Ag = S + ((size_t)b * NPOS + pos0) * C_;
  const u16* Bg = Pwt + (size_t)co0 * C_;

  // --- early residual prefetch for half 0 (issued before the GEMM; latency hides under it)
  const int st_row = t >> 5, st_sl = t & 31;   // store-loop coordinates
  float4 resA[8];
#pragma unroll
  for (int i = 0; i < 8; ++i) {
    const int idx = t + 256 * i;
    const int row = idx >> 5, sl = idx & 31;
    resA[i] = *(const float4*)(inp + ((size_t)b * C_ + co0 + row) * NPOS + pos0 + sl * 4);
  }

  f32x4 acc[4][4];
#pragma unroll
  for (int m = 0; m < 4; ++m)
#pragma unroll
    for (int n = 0; n < 4; ++n) { acc[m][n][0]=0.f; acc[m][n][1]=0.f; acc[m][n][2]=0.f; acc[m][n][3]=0.f; }

  uint4 ra[4], rb[4];
#define PJ_LOAD(KT)                                                        \
  _Pragma("unroll") for (int i = 0; i < 4; ++i) {                          \
    const int u = t + 256 * i, rr = u >> 3, ss = u & 7;                    \
    ra[i] = *(const uint4*)(Ag + (size_t)rr * C_ + (KT) * 64 + ss * 8);    \
    rb[i] = *(const uint4*)(Bg + (size_t)rr * C_ + (KT) * 64 + ss * 8);    \
  }
#define PJ_WRITE()                                                         \
  _Pragma("unroll") for (int i = 0; i < 4; ++i) {                          \
    const int u = t + 256 * i, rr = u >> 3, ss = u & 7;                    \
    const int sw = ((ss ^ (rr & 7)) << 3);                                 \
    *(uint4*)(Ab + rr * 64 + sw) = ra[i];                                  \
    *(uint4*)(Bb + rr * 64 + sw) = rb[i];                                  \
  }

  PJ_LOAD(0);
  PJ_WRITE();
  PJ_LOAD(1);
  __syncthreads();

  for (int kt = 0; kt < 4; ++kt) {
#pragma unroll
    for (int kk = 0; kk < 2; ++kk) {
      bf16x8 af[4], bfr[4];
#pragma unroll
      for (int m = 0; m < 4; ++m) {
        const int r = wm * 64 + m * 16 + (lane & 15);
        af[m] = *(const bf16x8*)(Ab + r * 64 + (((kk * 4 + g) ^ (r & 7)) << 3));
      }
#pragma unroll
      for (int n = 0; n < 4; ++n) {
        const int c = wn * 64 + n * 16 + (lane & 15);
        bfr[n] = *(const bf16x8*)(Bb + c * 64 + (((kk * 4 + g) ^ (c & 7)) << 3));
      }
#pragma unroll
      for (int m = 0; m < 4; ++m)
#pragma unroll
        for (int n = 0; n < 4; ++n)
          acc[m][n] = __builtin_amdgcn_mfma_f32_16x16x32_bf16(af[m], bfr[n], acc[m][n], 0, 0, 0);
    }
    if (kt < 3) {
      __syncthreads();
      PJ_WRITE();
      if (kt < 2) PJ_LOAD(kt + 2);
      __syncthreads();
    }
  }
#undef PJ_LOAD
#undef PJ_WRITE

  float4 resB[8];
  // ---- half 0 ----
  __syncthreads();
  if (wn == 0) {
#pragma unroll
    for (int n = 0; n < 4; ++n) {
      const int co_l = n * 16 + (lane & 15);
#pragma unroll
      for (int m = 0; m < 4; ++m) {
        const int pos_l = wm * 64 + m * 16 + (lane >> 4) * 4;
        const int slot = (pos_l >> 2) ^ (co_l & 7);
        const f32x4 a = acc[m][n];
        *(float4*)(SMF + co_l * 128 + slot * 4) = make_float4(a[0], a[1], a[2], a[3]);
      }
    }
  }
  __syncthreads();
  // issue half-1 residual loads (overlap with half-0 stores)
#pragma unroll
  for (int i = 0; i < 8; ++i) {
    const int idx = t + 256 * i;
    const int row = idx >> 5, sl = idx & 31;
    resB[i] = *(const float4*)(inp + ((size_t)b * C_ + co0 + 64 + row) * NPOS + pos0 + sl * 4);
  }
#pragma unroll
  for (int i = 0; i < 8; ++i) {
    const int idx = t + 256 * i;
    const int row = idx >> 5, sl = idx & 31;
    const float4 v = *(const float4*)(SMF + row * 128 + ((sl ^ (row & 7)) << 2));
    const int co = co0 + row;
    const float pb = proj_b[co];
    const size_t base = ((size_t)b * C_ + co) * NPOS + pos0 + sl * 4;
    const float4 res = resA[i];
    *(float4*)(outp + base) = make_float4(v.x + pb + res.x, v.y + pb + res.y,
                                          v.z + pb + res.z, v.w + pb + res.w);
  }
  // ---- half 1 ----
  __syncthreads();
  if (wn == 1) {
#pragma unroll
    for (int n = 0; n < 4; ++n) {
      const int co_l = n * 16 + (lane & 15);
#pragma unroll
      for (int m = 0; m < 4; ++m) {
        const int pos_l = wm * 64 + m * 16 + (lane >> 4) * 4;
        const int slot = (pos_l >> 2) ^ (co_l & 7);
        const f32x4 a = acc[m][n];
        *(float4*)(SMF + co_l * 128 + slot * 4) = make_float4(a[0], a[1], a[2], a[3]);
      }
    }
  }
  __syncthreads();
#pragma unroll
  for (int i = 0; i < 8; ++i) {
    const int idx = t + 256 * i;
    const int row = idx >> 5, sl = idx & 31;
    const float4 v = *(const float4*)(SMF + row * 128 + ((sl ^ (row & 7)) << 2));
    const int co = co0 + 64 + row;
    const float pb = proj_b[co];
    const size_t base = ((size_t)b * C_ + co) * NPOS + pos0 + sl * 4;
    const float4 res = resB[i];
    *(float4*)(outp + base) = make_float4(v.x + pb + res.x, v.y + pb + res.y,
                                          v.z + pb + res.z, v.w + pb + res.w);
  }
  (void)st_row; (void)st_sl;
}

extern "C" void kernel_launch(void* const* d_in, const int* in_sizes, int n_in,
                              void* d_out, int out_size, void* d_ws, size_t ws_size,
                              hipStream_t stream) {
  const float* input1 = (const float*)d_in[0];
  const float* input2 = (const float*)d_in[1];
  const float* guid   = (const float*)d_in[2];
  const float* kv_w   = (const float*)d_in[3];
  const float* kv_b   = (const float*)d_in[4];
  const float* q_w    = (const float*)d_in[5];
  const float* q_b    = (const float*)d_in[6];
  const float* proj_w = (const float*)d_in[7];
  const float* proj_b = (const float*)d_in[8];
  const float* dwc_w  = (const float*)d_in[9];
  const float* dwc_b  = (const float*)d_in[10];
  const float* an_b   = (const float*)d_in[11];
  const float* na_b   = (const float*)d_in[12];
  const float* ah_b   = (const float*)d_in[13];
  const float* aw_b   = (const float*)d_in[14];
  const float* ha_b   = (const float*)d_in[15];
  const float* wa_b   = (const float*)d_in[16];

  char* W = (char*)d_ws;
  u16* At1 = (u16*)W;        W += (size_t)B_ * NPOS * C_ * 2;
  u16* At2 = (u16*)W;        W += (size_t)B_ * NPOS * C_ * 2;
  u16* v1  = (u16*)W;        W += (size_t)B_ * NPOS * C_ * 2;
  u16* v2  = (u16*)W;        W += (size_t)B_ * NPOS * C_ * 2;
  u16* o1s = (u16*)W;        W += (size_t)B_ * NPOS * C_ * 2;
  u16* o2s = (u16*)W;        W += (size_t)B_ * NPOS * C_ * 2;
  u16* E   = (u16*)W;        W += (size_t)16 * NHA * NPOS * 2;
  float* T_p = (float*)W;    W += (size_t)16 * 8 * NHA * C_ * 4;
  u16* Wkt = (u16*)W;        W += (size_t)512 * C_ * 2;
  u16* Pwt = (u16*)W;        W += (size_t)C_ * C_ * 2;
  u16* wt  = (u16*)W;        W += (size_t)B_ * NHA * C_ * 2;
  float* posbT = (float*)W;  W += (size_t)NPOS * NHA * 4;
  float* kvbD   = (float*)W; W += (size_t)B_ * NHA * 4;
  float* lsumP  = (float*)W; W += (size_t)16 * 32 * NHA * 4;
  float* agent_v = (float*)W; W += (size_t)16 * NHA * HD * 4;
  float* dwcT    = (float*)W; W += (size_t)10 * 256 * 4;
  float* qd      = (float*)W; W += (size_t)B_ * NHA * 2 * 4;

  float* out1 = (float*)d_out;
  float* out2 = out1 + (size_t)B_ * C_ * NPOS;

  hipLaunchKernelGGL(k_bias, dim3((NHA * NPOS) / 256), dim3(256), 0, stream,
                     an_b, ah_b, aw_b, posbT);
  hipLaunchKernelGGL(k_prep_w, dim3(49), dim3(256), 0, stream,
                     kv_w, proj_w, dwc_w, dwc_b, Wkt, Pwt, dwcT);
  hipLaunchKernelGGL(k_wtilde, dim3(NH, B_), dim3(256), 0, stream,
                     Wkt, kv_b, guid, q_w, q_b, wt, kvbD, qd);
  hipLaunchKernelGGL(k_prep_in, dim3(64, 4, 16), dim3(256), 0, stream, input1, input2, At1, At2);
  hipLaunchKernelGGL(k_v_mfma, dim3(32, 2, 16), dim3(256), 0, stream,
                     At1, At2, Wkt, kv_b, v1, v2);
  hipLaunchKernelGGL(k_score, dim3(32, 1, 16), dim3(256), 0, stream,
                     At1, At2, wt, posbT, kvbD, E, lsumP);
  hipLaunchKernelGGL(k_pv, dim3(8, 2, 16), dim3(256), 0, stream, input1, input2, E, T_p);
  hipLaunchKernelGGL(k_agentv, dim3(NH, 16), dim3(256), 0, stream, T_p, lsumP, Wkt, kv_b, agent_v);
  hipLaunchKernelGGL(k_qattn, dim3(NPOS / 256, NH, 16), dim3(256), 0, stream,
                     guid, qd, agent_v, na_b, ha_b, wa_b, o1s, o2s);
  hipLaunchKernelGGL(k_dwconv, dim3(NPOS / 8, B_, 2), dim3(256), 0, stream,
                     v1, v2, dwcT, o1s, o2s);
  hipLaunchKernelGGL(k_proj_mfma, dim3(32, 2, 16), dim3(256), 0, stream,
                     o1s, o2s, Pwt, proj_b, input1, input2, out1, out2);
}

// Round 14
// 239.362 us; speedup vs baseline: 1.0138x; 1.0138x over previous
//
#include <hip/hip_runtime.h>
#include <hip/hip_bf16.h>
#include <cstddef>

#define B_   8
#define C_   256
#define HH   64
#define WW   64
#define NPOS 4096
#define NH   8
#define HD   32
#define NA   16
#define NHA  128      // NH*NA
#define SCALE 0.17677669529663687f

typedef unsigned short u16;
typedef __attribute__((ext_vector_type(8))) short bf16x8;
typedef __attribute__((ext_vector_type(4))) float f32x4;

__device__ __forceinline__ float bfbits2f(u16 u) {
  union { unsigned int i; float f; } x; x.i = ((unsigned int)u) << 16; return x.f;
}
__device__ __forceinline__ u16 f2bfbits(float f) {
  union { float f; unsigned int i; } x; x.f = f;
  unsigned int r = x.i + 0x7fffu + ((x.i >> 16) & 1u);
  return (u16)(r >> 16);
}
__device__ __forceinline__ void unpack8(const uint4 v, float* f) {
  f[0] = bfbits2f((u16)(v.x & 0xffff)); f[1] = bfbits2f((u16)(v.x >> 16));
  f[2] = bfbits2f((u16)(v.y & 0xffff)); f[3] = bfbits2f((u16)(v.y >> 16));
  f[4] = bfbits2f((u16)(v.z & 0xffff)); f[5] = bfbits2f((u16)(v.z >> 16));
  f[6] = bfbits2f((u16)(v.w & 0xffff)); f[7] = bfbits2f((u16)(v.w >> 16));
}

// ---------------- w~ = SCALE*(W_K agent) + kvb-dot + qd, with inline agent pooling ----------------
__global__ __launch_bounds__(256) void k_wtilde(const u16* __restrict__ Wkt, const float* __restrict__ kv_b,
                                                const float* __restrict__ g,
                                                const float* __restrict__ q_w, const float* __restrict__ q_b,
                                                u16* __restrict__ wt, float* __restrict__ kvbD,
                                                float* __restrict__ qd) {
  const int h = blockIdx.x, b = blockIdx.y;
  const int t = threadIdx.x;
  __shared__ u16 Wk[32 * 256];
  __shared__ float ags[16][32];
  __shared__ float red[256];
  __shared__ float gb[16];
  {
    const int ag = t >> 4, sub = t & 15;
    const int p1 = ag >> 2, p2 = ag & 3;
    const int yy = p1 * 16 + sub, xx0 = p2 * 16;
    const float* gp = g + (size_t)b * NPOS + yy * WW + xx0;
    float s = 0.f;
#pragma unroll
    for (int i = 0; i < 16; ++i) s += gp[i];
    red[t] = s;
  }
#pragma unroll
  for (int i = 0; i < 4; ++i) {
    const int idx = t + 256 * i;
    const int r = idx >> 5, sl = idx & 31;
    *(uint4*)(Wk + r * 256 + sl * 8) = *(const uint4*)(Wkt + (size_t)(h * 32 + r) * C_ + sl * 8);
  }
  __syncthreads();
  if ((t & 15) == 0) {
    const int ag = t >> 4;
    float tot = 0.f;
#pragma unroll
    for (int i = 0; i < 16; ++i) tot += red[(ag << 4) + i];
    gb[ag] = tot * (1.0f / 256.0f);
  }
  __syncthreads();
#pragma unroll
  for (int i = 0; i < 2; ++i) {
    const int idx = t + 256 * i;
    const int a = idx >> 5, d = idx & 31;
    ags[a][d] = (gb[a] * q_w[h * HD + d] + q_b[h * HD + d]) * SCALE;
  }
  __syncthreads();
  const int a = t >> 4, cb = (t & 15) * 16;
  float o[16];
#pragma unroll
  for (int k = 0; k < 16; ++k) o[k] = 0.f;
  for (int d = 0; d < 32; ++d) {
    const float av = ags[a][d];
#pragma unroll
    for (int k = 0; k < 16; ++k) o[k] += av * bfbits2f(Wk[d * 256 + cb + k]);
  }
  unsigned int w[8];
#pragma unroll
  for (int q = 0; q < 8; ++q)
    w[q] = (unsigned int)f2bfbits(o[2 * q]) | ((unsigned int)f2bfbits(o[2 * q + 1]) << 16);
  u16* op = wt + ((size_t)(b * NHA + h * 16 + a)) * C_ + cb;
  *(uint4*)op = make_uint4(w[0], w[1], w[2], w[3]);
  *(uint4*)(op + 8) = make_uint4(w[4], w[5], w[6], w[7]);
  if ((t & 15) == 0) {
    float s = 0.f;
#pragma unroll
    for (int d = 0; d < 32; ++d) s += ags[a][d] * kv_b[h * 32 + d];
    kvbD[b * NHA + h * 16 + a] = s;
  }
  if ((t & 15) == 1) {
    float s1 = 0.f, s2 = 0.f;
#pragma unroll
    for (int d = 0; d < 32; ++d) {
      s1 += ags[a][d] * q_w[h * HD + d];
      s2 += ags[a][d] * q_b[h * HD + d];
    }
    qd[(size_t)b * 256 + h * 32 + a * 2 + 0] = s1;
    qd[(size_t)b * 256 + h * 32 + a * 2 + 1] = s2;
  }
}

// ---------------- biases: posbT (pos, ha) f32 only ----------------
__global__ __launch_bounds__(256) void k_bias(const float* __restrict__ an_b,
                                              const float* __restrict__ ah_b, const float* __restrict__ aw_b,
                                              float* __restrict__ posbT) {
  const int idx = blockIdx.x * 256 + threadIdx.x;
  const int ha = idx & 127;
  const int pos = idx >> 7;
  const int h = ha >> 4, a = ha & 15;
  const int y = pos >> 6, x = pos & 63;
  const float sy = (y + 0.5f) * 0.0625f - 0.5f;
  const float sx = (x + 0.5f) * 0.0625f - 0.5f;
  const int y0 = (int)floorf(sy);
  const int x0 = (int)floorf(sx);
  const float wy = sy - (float)y0, wx = sx - (float)x0;
  const int y0c = min(max(y0, 0), 3), y1c = min(max(y0 + 1, 0), 3);
  const int x0c = min(max(x0, 0), 3), x1c = min(max(x0 + 1, 0), 3);
  const float* an4 = an_b + ((size_t)h * NA + a) * 16;
  const float pa_ = (1.f - wy) * ((1.f - wx) * an4[y0c * 4 + x0c] + wx * an4[y0c * 4 + x1c]) +
                    wy * ((1.f - wx) * an4[y1c * 4 + x0c] + wx * an4[y1c * 4 + x1c]);
  posbT[(size_t)pos * NHA + ha] = pa_ + ah_b[((size_t)h * NA + a) * HH + y] + aw_b[((size_t)h * NA + a) * WW + x];
}

// ---------------- transpose+convert inputs: in (b,c,n) f32 -> At (b,n,c) bf16 ----------------
__global__ __launch_bounds__(256) void k_prep_in(const float* __restrict__ in1, const float* __restrict__ in2,
                                                 u16* __restrict__ At1, u16* __restrict__ At2) {
  const int z = blockIdx.z;
  const int src = z >> 3, b = z & 7;
  const float* in = src ? in2 : in1;
  u16* At = src ? At2 : At1;
  const int pos0 = blockIdx.x * 64;
  const int ci0 = blockIdx.y * 64;
  __shared__ float tile[64][68];
  const int t = threadIdx.x;
  const int rpos = (t & 15) << 2, rci = t >> 4;
#pragma unroll
  for (int i = 0; i < 4; ++i) {
    const int ci_l = rci + 16 * i;
    const float4 v = *(const float4*)(in + ((size_t)b * C_ + ci0 + ci_l) * NPOS + pos0 + rpos);
    tile[ci_l][rpos + 0] = v.x; tile[ci_l][rpos + 1] = v.y;
    tile[ci_l][rpos + 2] = v.z; tile[ci_l][rpos + 3] = v.w;
  }
  __syncthreads();
#pragma unroll
  for (int i = 0; i < 2; ++i) {
    const int u = t + 256 * i;
    const int p = u >> 3, s = u & 7;
    unsigned int w[4];
#pragma unroll
    for (int q = 0; q < 4; ++q) {
      const u16 lo = f2bfbits(tile[s * 8 + 2 * q][p]);
      const u16 hi = f2bfbits(tile[s * 8 + 2 * q + 1][p]);
      w[q] = (unsigned int)lo | ((unsigned int)hi << 16);
    }
    *(uint4*)(At + ((size_t)(pos0 + p)) * C_ + (size_t)b * NPOS * C_ + ci0 + s * 8) =
        make_uint4(w[0], w[1], w[2], w[3]);
  }
}

// ---------------- transpose+convert weights (+ dwconv table as block 48) ----------------
__global__ __launch_bounds__(256) void k_prep_w(const float* __restrict__ kv_w, const float* __restrict__ proj_w,
                                                const float* __restrict__ dwc_w, const float* __restrict__ dwc_b,
                                                u16* __restrict__ Wkt, u16* __restrict__ Pwt,
                                                float* __restrict__ dwcT) {
  const int x = blockIdx.x;
  const int t = threadIdx.x;
  if (x == 48) {
    const int ci = t;
#pragma unroll
    for (int q = 0; q < 9; ++q) dwcT[q * 256 + ci] = dwc_w[ci * 9 + q];
    dwcT[9 * 256 + ci] = dwc_b[ci];
    return;
  }
  const float* W; u16* T; int j0, ci0, ncols;
  if (x < 32) { W = kv_w;  T = Wkt; j0 = (x & 7) * 64; ci0 = (x >> 3) * 64; ncols = 512; }
  else        { W = proj_w; T = Pwt; j0 = ((x - 32) & 3) * 64; ci0 = ((x - 32) >> 2) * 64; ncols = 256; }
  __shared__ float tile[64][68];
  const int rj = (t & 15) << 2, rci = t >> 4;
#pragma unroll
  for (int i = 0; i < 4; ++i) {
    const int ci_l = rci + 16 * i;
    const float4 v = *(const float4*)(W + (size_t)(ci0 + ci_l) * ncols + j0 + rj);
    tile[ci_l][rj + 0] = v.x; tile[ci_l][rj + 1] = v.y;
    tile[ci_l][rj + 2] = v.z; tile[ci_l][rj + 3] = v.w;
  }
  __syncthreads();
#pragma unroll
  for (int i = 0; i < 2; ++i) {
    const int u = t + 256 * i;
    const int p = u >> 3, s = u & 7;
    unsigned int w[4];
#pragma unroll
    for (int q = 0; q < 4; ++q) {
      const u16 lo = f2bfbits(tile[s * 8 + 2 * q][p]);
      const u16 hi = f2bfbits(tile[s * 8 + 2 * q + 1][p]);
      w[q] = (unsigned int)lo | ((unsigned int)hi << 16);
    }
    *(uint4*)(T + (size_t)(j0 + p) * C_ + ci0 + s * 8) = make_uint4(w[0], w[1], w[2], w[3]);
  }
}

// ---------------- V projection only: V[b,pos,256] = At @ Wv + bv ----------------
__global__ __launch_bounds__(256) void k_v_mfma(const u16* __restrict__ At1, const u16* __restrict__ At2,
                                                const u16* __restrict__ Wkt, const float* __restrict__ kv_b,
                                                u16* __restrict__ v1, u16* __restrict__ v2) {
  const int z = blockIdx.z;
  const int src = z >> 3, b = z & 7;
  const u16* At = src ? At2 : At1;
  u16* vout = src ? v2 : v1;
  const int pos0 = blockIdx.x * 128;
  const int j0 = blockIdx.y * 128;

  __shared__ __align__(16) u16 SM[16384];
  u16* Ab = SM;
  u16* Bb = SM + 8192;

  const int t = threadIdx.x;
  const int wave = t >> 6, lane = t & 63;
  const int wm = wave >> 1, wn = wave & 1;
  const int g = lane >> 4;

  const u16* Ag = Wkt + (size_t)(256 + j0) * C_;
  const u16* Bg = At + ((size_t)b * NPOS + pos0) * C_;

  f32x4 acc[4][4];
#pragma unroll
  for (int m = 0; m < 4; ++m)
#pragma unroll
    for (int n = 0; n < 4; ++n) { acc[m][n][0]=0.f; acc[m][n][1]=0.f; acc[m][n][2]=0.f; acc[m][n][3]=0.f; }

  uint4 ra[4], rb[4];
#define V_LOAD(KT)                                                         \
  _Pragma("unroll") for (int i = 0; i < 4; ++i) {                          \
    const int u = t + 256 * i, rr = u >> 3, ss = u & 7;                    \
    ra[i] = *(const uint4*)(Ag + (size_t)rr * C_ + (KT) * 64 + ss * 8);    \
    rb[i] = *(const uint4*)(Bg + (size_t)rr * C_ + (KT) * 64 + ss * 8);    \
  }
#define V_WRITE()                                                          \
  _Pragma("unroll") for (int i = 0; i < 4; ++i) {                          \
    const int u = t + 256 * i, rr = u >> 3, ss = u & 7;                    \
    const int sw = ((ss ^ (rr & 7)) << 3);                                 \
    *(uint4*)(Ab + rr * 64 + sw) = ra[i];                                  \
    *(uint4*)(Bb + rr * 64 + sw) = rb[i];                                  \
  }

  V_LOAD(0);
  V_WRITE();
  V_LOAD(1);
  __syncthreads();

  for (int kt = 0; kt < 4; ++kt) {
#pragma unroll
    for (int kk = 0; kk < 2; ++kk) {
      bf16x8 af[4], bfr[4];
#pragma unroll
      for (int m = 0; m < 4; ++m) {
        const int r = wm * 64 + m * 16 + (lane & 15);
        af[m] = *(const bf16x8*)(Ab + r * 64 + (((kk * 4 + g) ^ (r & 7)) << 3));
      }
#pragma unroll
      for (int n = 0; n < 4; ++n) {
        const int c = wn * 64 + n * 16 + (lane & 15);
        bfr[n] = *(const bf16x8*)(Bb + c * 64 + (((kk * 4 + g) ^ (c & 7)) << 3));
      }
#pragma unroll
      for (int m = 0; m < 4; ++m)
#pragma unroll
        for (int n = 0; n < 4; ++n)
          acc[m][n] = __builtin_amdgcn_mfma_f32_16x16x32_bf16(af[m], bfr[n], acc[m][n], 0, 0, 0);
    }
    if (kt < 3) {
      __syncthreads();
      V_WRITE();
      if (kt < 2) V_LOAD(kt + 2);
      __syncthreads();
    }
  }
#undef V_LOAD
#undef V_WRITE

  __syncthreads();
#pragma unroll
  for (int m = 0; m < 4; ++m) {
    const int jl = wm * 64 + m * 16 + (lane >> 4) * 4;
    const float4 bv = *(const float4*)(kv_b + 256 + j0 + jl);
#pragma unroll
    for (int n = 0; n < 4; ++n) {
      const int pos_l = wn * 64 + n * 16 + (lane & 15);
      const f32x4 a = acc[m][n];
      ushort4 st;
      st.x = f2bfbits(a[0] + bv.x); st.y = f2bfbits(a[1] + bv.y);
      st.z = f2bfbits(a[2] + bv.z); st.w = f2bfbits(a[3] + bv.w);
      const int slot = (jl >> 3) ^ (pos_l & 7);
      *(ushort4*)(SM + pos_l * 128 + slot * 8 + (jl & 7)) = st;
    }
  }
  __syncthreads();
#pragma unroll
  for (int i = 0; i < 8; ++i) {
    const int idx = t + 256 * i;
    const int row = idx >> 4, sl = idx & 15;
    const uint4 v = *(const uint4*)(SM + row * 128 + ((sl ^ (row & 7)) << 3));
    *(uint4*)(vout + ((size_t)b * NPOS + pos0 + row) * C_ + j0 + sl * 8) = v;
  }
}

// ---------------- score GEMM: E[sb,ha,pos] = exp(At @ wt^T + posbT + kvbD) bf16, + row sums ----------------
__global__ __launch_bounds__(256) void k_score(const u16* __restrict__ At1, const u16* __restrict__ At2,
                                               const u16* __restrict__ wt, const float* __restrict__ posbT,
                                               const float* __restrict__ kvbD,
                                               u16* __restrict__ E, float* __restrict__ lsumP) {
  const int z = blockIdx.z;
  const int src = z >> 3, b = z & 7;
  const int sb = src * 8 + b;
  const u16* At = src ? At2 : At1;
  const int pos0 = blockIdx.x * 128;

  __shared__ __align__(16) u16 SM[16384];
  __shared__ float lsum_sm[2][128];
  u16* Ab = SM;
  u16* Bb = SM + 8192;

  const int t = threadIdx.x;
  const int wave = t >> 6, lane = t & 63;
  const int wm = wave >> 1, wn = wave & 1;
  const int g = lane >> 4;

  const u16* Ag = At + ((size_t)b * NPOS + pos0) * C_;
  const u16* Bg = wt + (size_t)b * NHA * C_;

  f32x4 acc[4][4];
#pragma unroll
  for (int m = 0; m < 4; ++m)
#pragma unroll
    for (int n = 0; n < 4; ++n) { acc[m][n][0]=0.f; acc[m][n][1]=0.f; acc[m][n][2]=0.f; acc[m][n][3]=0.f; }

  uint4 ra[4], rb[4];
#define S_LOAD(KT)                                                         \
  _Pragma("unroll") for (int i = 0; i < 4; ++i) {                          \
    const int u = t + 256 * i, rr = u >> 3, ss = u & 7;                    \
    ra[i] = *(const uint4*)(Ag + (size_t)rr * C_ + (KT) * 64 + ss * 8);    \
    rb[i] = *(const uint4*)(Bg + (size_t)rr * C_ + (KT) * 64 + ss * 8);    \
  }
#define S_WRITE()                                                          \
  _Pragma("unroll") for (int i = 0; i < 4; ++i) {                          \
    const int u = t + 256 * i, rr = u >> 3, ss = u & 7;                    \
    const int sw = ((ss ^ (rr & 7)) << 3);                                 \
    *(uint4*)(Ab + rr * 64 + sw) = ra[i];                                  \
    *(uint4*)(Bb + rr * 64 + sw) = rb[i];                                  \
  }

  S_LOAD(0);
  S_WRITE();
  S_LOAD(1);
  __syncthreads();

  for (int kt = 0; kt < 4; ++kt) {
#pragma unroll
    for (int kk = 0; kk < 2; ++kk) {
      bf16x8 af[4], bfr[4];
#pragma unroll
      for (int m = 0; m < 4; ++m) {
        const int r = wm * 64 + m * 16 + (lane & 15);
        af[m] = *(const bf16x8*)(Ab + r * 64 + (((kk * 4 + g) ^ (r & 7)) << 3));
      }
#pragma unroll
      for (int n = 0; n < 4; ++n) {
        const int c = wn * 64 + n * 16 + (lane & 15);
        bfr[n] = *(const bf16x8*)(Bb + c * 64 + (((kk * 4 + g) ^ (c & 7)) << 3));
      }
#pragma unroll
      for (int m = 0; m < 4; ++m)
#pragma unroll
        for (int n = 0; n < 4; ++n)
          acc[m][n] = __builtin_amdgcn_mfma_f32_16x16x32_bf16(af[m], bfr[n], acc[m][n], 0, 0, 0);
    }
    if (kt < 3) {
      __syncthreads();
      S_WRITE();
      if (kt < 2) S_LOAD(kt + 2);
      __syncthreads();
    }
  }
#undef S_LOAD
#undef S_WRITE

  __syncthreads();
  float ls[4] = {0.f, 0.f, 0.f, 0.f};
#pragma unroll
  for (int n = 0; n < 4; ++n) {
    const int ha_l = wn * 64 + n * 16 + (lane & 15);
    const float kb = kvbD[b * NHA + ha_l];
#pragma unroll
    for (int m = 0; m < 4; ++m) {
      const int pos_l = wm * 64 + m * 16 + (lane >> 4) * 4;
      float e[4];
#pragma unroll
      for (int j = 0; j < 4; ++j) {
        const float s = acc[m][n][j] + posbT[(size_t)(pos0 + pos_l + j) * NHA + ha_l] + kb;
        e[j] = __expf(s);
        ls[n] += e[j];
      }
      ushort4 st;
      st.x = f2bfbits(e[0]); st.y = f2bfbits(e[1]); st.z = f2bfbits(e[2]); st.w = f2bfbits(e[3]);
      const int sw = (pos_l >> 3) ^ (ha_l & 15);
      *(ushort4*)(SM + ha_l * 128 + sw * 8 + (pos_l & 7)) = st;
    }
  }
#pragma unroll
  for (int n = 0; n < 4; ++n) {
    float v = ls[n];
    v += __shfl_xor(v, 16);
    v += __shfl_xor(v, 32);
    ls[n] = v;
  }
  if (lane < 16) {
#pragma unroll
    for (int n = 0; n < 4; ++n) lsum_sm[wm][wn * 64 + n * 16 + lane] = ls[n];
  }
  __syncthreads();
  if (t < 128)
    lsumP[((size_t)sb * 32 + blockIdx.x) * NHA + t] = lsum_sm[0][t] + lsum_sm[1][t];
#pragma unroll
  for (int i = 0; i < 8; ++i) {
    const int idx = t + 256 * i;
    const int row = idx >> 4, sl = idx & 15;
    const uint4 v = *(const uint4*)(SM + row * 128 + ((sl ^ (row & 15)) << 3));
    *(uint4*)(E + ((size_t)sb * NHA + row) * NPOS + pos0 + sl * 8) = v;
  }
}

// ---------------- PV GEMM: T_p[sb,kc,ha,ci] = sum_pos in[ci,pos] * E[ha,pos] ----------------
__global__ __launch_bounds__(256) void k_pv(const float* __restrict__ in1, const float* __restrict__ in2,
                                            const u16* __restrict__ E, float* __restrict__ T_p) {
  const int kc = blockIdx.x;
  const int ci0 = blockIdx.y * 128;
  const int sb = blockIdx.z;
  const int src = sb >> 3, b = sb & 7;
  const float* in = src ? in2 : in1;
  const int kpos0 = kc * 512;

  __shared__ __align__(16) u16 As[8192];
  __shared__ __align__(16) u16 Bs[8192];

  const int t = threadIdx.x;
  const int wave = t >> 6, lane = t & 63;
  const int wm = wave >> 1, wn = wave & 1;
  const int g = lane >> 4;

  const float* Ain = in + (size_t)b * C_ * NPOS;
  const u16* Eg = E + (size_t)sb * NHA * NPOS;

  f32x4 acc[4][4];
#pragma unroll
  for (int m = 0; m < 4; ++m)
#pragma unroll
    for (int n = 0; n < 4; ++n) { acc[m][n][0]=0.f; acc[m][n][1]=0.f; acc[m][n][2]=0.f; acc[m][n][3]=0.f; }

  float4 pa[8];
  uint4 pb[4];
#define PV_LOAD(KT)                                                            \
  _Pragma("unroll") for (int i = 0; i < 8; ++i) {                              \
    const int idx = t + 256 * i, rr = idx >> 4, fq = idx & 15;                 \
    pa[i] = *(const float4*)(Ain + (size_t)(ci0 + rr) * NPOS + kpos0 + (KT) * 64 + fq * 4); \
  }                                                                            \
  _Pragma("unroll") for (int i = 0; i < 4; ++i) {                              \
    const int idx = t + 256 * i, rr = idx >> 3, ss = idx & 7;                  \
    pb[i] = *(const uint4*)(Eg + (size_t)rr * NPOS + kpos0 + (KT) * 64 + ss * 8); \
  }
#define PV_WRITE()                                                             \
  _Pragma("unroll") for (int i = 0; i < 8; ++i) {                              \
    const int idx = t + 256 * i, rr = idx >> 4, fq = idx & 15;                 \
    ushort4 st;                                                                \
    st.x = f2bfbits(pa[i].x); st.y = f2bfbits(pa[i].y);                        \
    st.z = f2bfbits(pa[i].z); st.w = f2bfbits(pa[i].w);                        \
    const int sw = ((fq >> 1) ^ (rr & 7));                                     \
    *(ushort4*)(As + rr * 64 + sw * 8 + (fq & 1) * 4) = st;                    \
  }                                                                            \
  _Pragma("unroll") for (int i = 0; i < 4; ++i) {                              \
    const int idx = t + 256 * i, rr = idx >> 3, ss = idx & 7;                  \
    *(uint4*)(Bs + rr * 64 + ((ss ^ (rr & 7)) << 3)) = pb[i];                  \
  }

  PV_LOAD(0);
  PV_WRITE();
  PV_LOAD(1);
  __syncthreads();

  for (int kt = 0; kt < 8; ++kt) {
#pragma unroll
    for (int kk = 0; kk < 2; ++kk) {
      bf16x8 af[4], bfr[4];
#pragma unroll
      for (int m = 0; m < 4; ++m) {
        const int r = wm * 64 + m * 16 + (lane & 15);
        af[m] = *(const bf16x8*)(As + r * 64 + (((kk * 4 + g) ^ (r & 7)) << 3));
      }
#pragma unroll
      for (int n = 0; n < 4; ++n) {
        const int c = wn * 64 + n * 16 + (lane & 15);
        bfr[n] = *(const bf16x8*)(Bs + c * 64 + (((kk * 4 + g) ^ (c & 7)) << 3));
      }
#pragma unroll
      for (int m = 0; m < 4; ++m)
#pragma unroll
        for (int n = 0; n < 4; ++n)
          acc[m][n] = __builtin_amdgcn_mfma_f32_16x16x32_bf16(af[m], bfr[n], acc[m][n], 0, 0, 0);
    }
    if (kt < 7) {
      __syncthreads();
      PV_WRITE();
      if (kt < 6) PV_LOAD(kt + 2);
      __syncthreads();
    }
  }
#undef PV_LOAD
#undef PV_WRITE

#pragma unroll
  for (int m = 0; m < 4; ++m) {
    const int ci_l = wm * 64 + m * 16 + (lane >> 4) * 4;
#pragma unroll
    for (int n = 0; n < 4; ++n) {
      const int ha_l = wn * 64 + n * 16 + (lane & 15);
      const f32x4 a = acc[m][n];
      *(float4*)(T_p + (((size_t)sb * 8 + kc) * NHA + ha_l) * C_ + ci0 + ci_l) =
          make_float4(a[0], a[1], a[2], a[3]);
    }
  }
}

// ---------------- agent_v = (sum_kc T)/lsum @ Wv + bv ----------------
__global__ __launch_bounds__(256) void k_agentv(const float* __restrict__ T_p, const float* __restrict__ lsumP,
                                                const u16* __restrict__ Wkt, const float* __restrict__ kv_b,
                                                float* __restrict__ agent_v) {
  const int h = blockIdx.x, sb = blockIdx.y;
  const int t = threadIdx.x;
  __shared__ float Tred[16 * 256];
  __shared__ u16 Wv[32 * 256];
  __shared__ float lsum_s[16];
#pragma unroll
  for (int i = 0; i < 4; ++i) {
    const int idx = t + 256 * i;
    const int r = idx >> 5, sl = idx & 31;
    *(uint4*)(Wv + r * 256 + sl * 8) = *(const uint4*)(Wkt + (size_t)(256 + h * 32 + r) * C_ + sl * 8);
  }
#pragma unroll
  for (int i = 0; i < 16; ++i) {
    const int idx = t + 256 * i;
    const int a = idx >> 8, ci = idx & 255;
    float s = 0.f;
#pragma unroll
    for (int kc = 0; kc < 8; ++kc)
      s += T_p[(((size_t)sb * 8 + kc) * NHA + h * 16 + a) * C_ + ci];
    Tred[a * 256 + ci] = s;
  }
  if (t < 16) {
    float s = 0.f;
#pragma unroll
    for (int pt = 0; pt < 32; ++pt) s += lsumP[((size_t)sb * 32 + pt) * NHA + h * 16 + t];
    lsum_s[t] = s;
  }
  __syncthreads();
  const int a = t >> 4, dp = (t & 15) * 2;
  float o0 = 0.f, o1 = 0.f;
  const float* Tr = Tred + a * 256;
  for (int ci = 0; ci < 256; ++ci) {
    const float tv = Tr[ci];
    o0 += tv * bfbits2f(Wv[dp * 256 + ci]);
    o1 += tv * bfbits2f(Wv[(dp + 1) * 256 + ci]);
  }
  const float inv = 1.0f / lsum_s[a];
  float* op = agent_v + (size_t)sb * NHA * HD + (h * 16 + a) * HD + dp;
  op[0] = o0 * inv + kv_b[256 + h * 32 + dp];
  op[1] = o1 * inv + kv_b[256 + h * 32 + dp + 1];
}

// ---------------- query attention: one src per block, inline agent-bias ----------------
__global__ __launch_bounds__(256) void k_qattn(const float* __restrict__ g,
                                               const float* __restrict__ qd,
                                               const float* __restrict__ agent_v,
                                               const float* __restrict__ na_b,
                                               const float* __restrict__ ha_b,
                                               const float* __restrict__ wa_b,
                                               u16* __restrict__ o1s, u16* __restrict__ o2s) {
  const int h = blockIdx.y;
  const int sb = blockIdx.z;
  const int src = sb >> 3, b = sb & 7;
  u16* out = src ? o2s : o1s;
  const int t = threadIdx.x;
  const int pos = blockIdx.x * 256 + t;
  __shared__ float dotW[16], dotB[16];
  __shared__ float av[16][32];
  __shared__ float nab[16][16];
  for (int idx = t; idx < 512; idx += 256) {
    const int a = idx >> 5, d = idx & 31;
    av[a][d] = agent_v[(size_t)sb * NHA * HD + (h * 16 + a) * HD + d];
  }
  if (t < 256 && t < 16 * 16) {
    const int a = t >> 4, q = t & 15;
    nab[a][q] = na_b[((size_t)h * NA + a) * 16 + q];
  }
  if (t < 16) {
    dotW[t] = qd[(size_t)b * 256 + h * 32 + t * 2 + 0];
    dotB[t] = qd[(size_t)b * 256 + h * 32 + t * 2 + 1];
  }
  __syncthreads();
  const int y = pos >> 6, x = pos & 63;
  const float sy = (y + 0.5f) * 0.0625f - 0.5f;
  const float sx = (x + 0.5f) * 0.0625f - 0.5f;
  const int y0 = (int)floorf(sy);
  const int x0 = (int)floorf(sx);
  const float wy = sy - (float)y0, wx = sx - (float)x0;
  const int y0c = min(max(y0, 0), 3), y1c = min(max(y0 + 1, 0), 3);
  const int x0c = min(max(x0, 0), 3), x1c = min(max(x0 + 1, 0), 3);
  const float c00 = (1.f - wy) * (1.f - wx), c01 = (1.f - wy) * wx;
  const float c10 = wy * (1.f - wx), c11 = wy * wx;
  const int i00 = y0c * 4 + x0c, i01 = y0c * 4 + x1c;
  const int i10 = y1c * 4 + x0c, i11 = y1c * 4 + x1c;
  const float* hp = ha_b + ((size_t)h * HH + y) * NA;
  const float* wp = wa_b + ((size_t)h * WW + x) * NA;
  const float gv = g[(size_t)b * NPOS + pos];
  float s[16];
  float m = -1e30f;
#pragma unroll
  for (int a = 0; a < 16; ++a) {
    const float nv = c00 * nab[a][i00] + c01 * nab[a][i01] + c10 * nab[a][i10] + c11 * nab[a][i11];
    s[a] = gv * dotW[a] + dotB[a] + nv + hp[a] + wp[a];
    m = fmaxf(m, s[a]);
  }
  float l = 0.f;
#pragma unroll
  for (int a = 0; a < 16; ++a) {
    s[a] = __expf(s[a] - m);
    l += s[a];
  }
  const float inv = 1.0f / l;
  float o[32] = {};
#pragma unroll
  for (int a = 0; a < 16; ++a) {
    const float pa = s[a] * inv;
#pragma unroll
    for (int q = 0; q < 8; ++q) {
      const float4 v4 = *(const float4*)&av[a][q * 4];
      o[q * 4 + 0] += pa * v4.x; o[q * 4 + 1] += pa * v4.y;
      o[q * 4 + 2] += pa * v4.z; o[q * 4 + 3] += pa * v4.w;
    }
  }
  u16* op = out + ((size_t)b * NPOS + pos) * C_ + h * HD;
#pragma unroll
  for (int blk = 0; blk < 4; ++blk) {
    unsigned int w1[4];
#pragma unroll
    for (int q = 0; q < 4; ++q)
      w1[q] = (unsigned int)f2bfbits(o[blk * 8 + 2 * q]) | ((unsigned int)f2bfbits(o[blk * 8 + 2 * q + 1]) << 16);
    *(uint4*)(op + blk * 8) = make_uint4(w1[0], w1[1], w1[2], w1[3]);
  }
}

// ---------------- depthwise 3x3 conv: 8ch/thread vectorized, RMW o1s/o2s ----------------
__global__ __launch_bounds__(256) void k_dwconv(const u16* __restrict__ v1, const u16* __restrict__ v2,
                                                const float* __restrict__ dwcT,
                                                u16* __restrict__ o1s, u16* __restrict__ o2s) {
  const u16* V = blockIdx.z ? v2 : v1;
  u16* out = blockIdx.z ? o2s : o1s;
  const int b = blockIdx.y;
  const int t = threadIdx.x;
  const int cg = t & 31;
  const int ch = cg * 8;
  const int px = t >> 5;
  const int pos = (blockIdx.x << 3) + px;
  const int y = pos >> 6, x = pos & 63;

  float acc[8];
  {
    const float4 b0 = *(const float4*)(dwcT + 9 * 256 + ch);
    const float4 b1 = *(const float4*)(dwcT + 9 * 256 + ch + 4);
    acc[0] = b0.x; acc[1] = b0.y; acc[2] = b0.z; acc[3] = b0.w;
    acc[4] = b1.x; acc[5] = b1.y; acc[6] = b1.z; acc[7] = b1.w;
  }
  const u16* vb = V + (size_t)b * NPOS * C_ + ch;
#pragma unroll
  for (int dy = -1; dy <= 1; ++dy) {
    const int yy = y + dy;
    if (yy < 0 || yy > 63) continue;
#pragma unroll
    for (int dx = -1; dx <= 1; ++dx) {
      const int xx = x + dx;
      if (xx < 0 || xx > 63) continue;
      const int q = (dy + 1) * 3 + (dx + 1);
      const float4 w0 = *(const float4*)(dwcT + q * 256 + ch);
      const float4 w1 = *(const float4*)(dwcT + q * 256 + ch + 4);
      const uint4 vv = *(const uint4*)(vb + (size_t)(yy * 64 + xx) * C_);
      float f8[8];
      unpack8(vv, f8);
      acc[0] += w0.x * f8[0]; acc[1] += w0.y * f8[1];
      acc[2] += w0.z * f8[2]; acc[3] += w0.w * f8[3];
      acc[4] += w1.x * f8[4]; acc[5] += w1.y * f8[5];
      acc[6] += w1.z * f8[6]; acc[7] += w1.w * f8[7];
    }
  }
  u16* op = out + ((size_t)b * NPOS + pos) * C_ + ch;
  const uint4 ov = *(const uint4*)op;
  float f8[8];
  unpack8(ov, f8);
  unsigned int wo[4];
#pragma unroll
  for (int q2 = 0; q2 < 4; ++q2)
    wo[q2] = (unsigned int)f2bfbits(f8[2 * q2] + acc[2 * q2]) |
             ((unsigned int)f2bfbits(f8[2 * q2 + 1] + acc[2 * q2 + 1]) << 16);
  *(uint4*)op = make_uint4(wo[0], wo[1], wo[2], wo[3]);
}

// ---------------- output projection, bf16 MFMA -> (b,c,n) f32 + bias + residual ----------------
__global__ __launch_bounds__(256) void k_proj_mfma(const u16* __restrict__ o1s, const u16* __restrict__ o2s,
                                                   const u16* __restrict__ Pwt, const float* __restrict__ proj_b,
                                                   const float* __restrict__ in1, const float* __restrict__ in2,
                                                   float* __restrict__ out1, float* __restrict__ out2) {
  const int z = blockIdx.z;
  const int src = z >> 3, b = z & 7;
  const u16* S = src ? o2s : o1s;
  const float* inp = src ? in2 : in1;
  float* outp = src ? out2 : out1;
  const int pos0 = blockIdx.x * 128;
  const int co0 = blockIdx.y * 128;

  __shared__ __align__(16) u16 SM[16384];
  u16* Ab = SM;
  u16* Bb = SM + 8192;
  float* SMF = (float*)SM;

  const int t = threadIdx.x;
  const int wave = t >> 6, lane = t & 63;
  const int wm = wave >> 1, wn = wave & 1;
  const int g = lane >> 4;

  const u16* Ag = S + ((size_t)b * NPOS + pos0) * C_;
  const u16* Bg = Pwt + (size_t)co0 * C_;

  f32x4 acc[4][4];
#pragma unroll
  for (int m = 0; m < 4; ++m)
#pragma unroll
    for (int n = 0; n < 4; ++n) { acc[m][n][0]=0.f; acc[m][n][1]=0.f; acc[m][n][2]=0.f; acc[m][n][3]=0.f; }

  uint4 ra[4], rb[4];
#define PJ_LOAD(KT)                                                        \
  _Pragma("unroll") for (int i = 0; i < 4; ++i) {                          \
    const int u = t + 256 * i, rr = u >> 3, ss = u & 7;                    \
    ra[i] = *(const uint4*)(Ag + (size_t)rr * C_ + (KT) * 64 + ss * 8);    \
    rb[i] = *(const uint4*)(Bg + (size_t)rr * C_ + (KT) * 64 + ss * 8);    \
  }
#define PJ_WRITE()                                                         \
  _Pragma("unroll") for (int i = 0; i < 4; ++i) {                          \
    const int u = t + 256 * i, rr = u >> 3, ss = u & 7;                    \
    const int sw = ((ss ^ (rr & 7)) << 3);                                 \
    *(uint4*)(Ab + rr * 64 + sw) = ra[i];                                  \
    *(uint4*)(Bb + rr * 64 + sw) = rb[i];                                  \
  }

  PJ_LOAD(0);
  PJ_WRITE();
  PJ_LOAD(1);
  __syncthreads();

  for (int kt = 0; kt < 4; ++kt) {
#pragma unroll
    for (int kk = 0; kk < 2; ++kk) {
      bf16x8 af[4], bfr[4];
#pragma unroll
      for (int m = 0; m < 4; ++m) {
        const int r = wm * 64 + m * 16 + (lane & 15);
        af[m] = *(const bf16x8*)(Ab + r * 64 + (((kk * 4 + g) ^ (r & 7)) << 3));
      }
#pragma unroll
      for (int n = 0; n < 4; ++n) {
        const int c = wn * 64 + n * 16 + (lane & 15);
        bfr[n] = *(const bf16x8*)(Bb + c * 64 + (((kk * 4 + g) ^ (c & 7)) << 3));
      }
#pragma unroll
      for (int m = 0; m < 4; ++m)
#pragma unroll
        for (int n = 0; n < 4; ++n)
          acc[m][n] = __builtin_amdgcn_mfma_f32_16x16x32_bf16(af[m], bfr[n], acc[m][n], 0, 0, 0);
    }
    if (kt < 3) {
      __syncthreads();
      PJ_WRITE();
      if (kt < 2) PJ_LOAD(kt + 2);
      __syncthreads();
    }
  }
#undef PJ_LOAD
#undef PJ_WRITE

#pragma unroll
  for (int hf = 0; hf < 2; ++hf) {
    __syncthreads();
    if (wn == hf) {
#pragma unroll
      for (int n = 0; n < 4; ++n) {
        const int co_l = n * 16 + (lane & 15);
#pragma unroll
        for (int m = 0; m < 4; ++m) {
          const int pos_l = wm * 64 + m * 16 + (lane >> 4) * 4;
          const int slot = (pos_l >> 2) ^ (co_l & 7);
          const f32x4 a = acc[m][n];
          *(float4*)(SMF + co_l * 128 + slot * 4) = make_float4(a[0], a[1], a[2], a[3]);
        }
      }
    }
    __syncthreads();
#pragma unroll
    for (int i = 0; i < 8; ++i) {
      const int idx = t + 256 * i;
      const int row = idx >> 5, sl = idx & 31;
      const float4 v = *(const float4*)(SMF + row * 128 + ((sl ^ (row & 7)) << 2));
      const int co = co0 + hf * 64 + row;
      const float pb = proj_b[co];
      const size_t base = ((size_t)b * C_ + co) * NPOS + pos0 + sl * 4;
      const float4 res = *(const float4*)(inp + base);
      *(float4*)(outp + base) = make_float4(v.x + pb + res.x, v.y + pb + res.y,
                                            v.z + pb + res.z, v.w + pb + res.w);
    }
  }
}

extern "C" void kernel_launch(void* const* d_in, const int* in_sizes, int n_in,
                              void* d_out, int out_size, void* d_ws, size_t ws_size,
                              hipStream_t stream) {
  const float* input1 = (const float*)d_in[0];
  const float* input2 = (const float*)d_in[1];
  const float* guid   = (const float*)d_in[2];
  const float* kv_w   = (const float*)d_in[3];
  const float* kv_b   = (const float*)d_in[4];
  const float* q_w    = (const float*)d_in[5];
  const float* q_b    = (const float*)d_in[6];
  const float* proj_w = (const float*)d_in[7];
  const float* proj_b = (const float*)d_in[8];
  const float* dwc_w  = (const float*)d_in[9];
  const float* dwc_b  = (const float*)d_in[10];
  const float* an_b   = (const float*)d_in[11];
  const float* na_b   = (const float*)d_in[12];
  const float* ah_b   = (const float*)d_in[13];
  const float* aw_b   = (const float*)d_in[14];
  const float* ha_b   = (const float*)d_in[15];
  const float* wa_b   = (const float*)d_in[16];

  char* W = (char*)d_ws;
  u16* At1 = (u16*)W;        W += (size_t)B_ * NPOS * C_ * 2;
  u16* At2 = (u16*)W;        W += (size_t)B_ * NPOS * C_ * 2;
  u16* v1  = (u16*)W;        W += (size_t)B_ * NPOS * C_ * 2;
  u16* v2  = (u16*)W;        W += (size_t)B_ * NPOS * C_ * 2;
  u16* o1s = (u16*)W;        W += (size_t)B_ * NPOS * C_ * 2;
  u16* o2s = (u16*)W;        W += (size_t)B_ * NPOS * C_ * 2;
  u16* E   = (u16*)W;        W += (size_t)16 * NHA * NPOS * 2;
  float* T_p = (float*)W;    W += (size_t)16 * 8 * NHA * C_ * 4;
  u16* Wkt = (u16*)W;        W += (size_t)512 * C_ * 2;
  u16* Pwt = (u16*)W;        W += (size_t)C_ * C_ * 2;
  u16* wt  = (u16*)W;        W += (size_t)B_ * NHA * C_ * 2;
  float* posbT = (float*)W;  W += (size_t)NPOS * NHA * 4;
  float* kvbD   = (float*)W; W += (size_t)B_ * NHA * 4;
  float* lsumP  = (float*)W; W += (size_t)16 * 32 * NHA * 4;
  float* agent_v = (float*)W; W += (size_t)16 * NHA * HD * 4;
  float* dwcT    = (float*)W; W += (size_t)10 * 256 * 4;
  float* qd      = (float*)W; W += (size_t)B_ * NHA * 2 * 4;

  float* out1 = (float*)d_out;
  float* out2 = out1 + (size_t)B_ * C_ * NPOS;

  hipLaunchKernelGGL(k_bias, dim3((NHA * NPOS) / 256), dim3(256), 0, stream,
                     an_b, ah_b, aw_b, posbT);
  hipLaunchKernelGGL(k_prep_w, dim3(49), dim3(256), 0, stream,
                     kv_w, proj_w, dwc_w, dwc_b, Wkt, Pwt, dwcT);
  hipLaunchKernelGGL(k_wtilde, dim3(NH, B_), dim3(256), 0, stream,
                     Wkt, kv_b, guid, q_w, q_b, wt, kvbD, qd);
  hipLaunchKernelGGL(k_prep_in, dim3(64, 4, 16), dim3(256), 0, stream, input1, input2, At1, At2);
  hipLaunchKernelGGL(k_v_mfma, dim3(32, 2, 16), dim3(256), 0, stream,
                     At1, At2, Wkt, kv_b, v1, v2);
  hipLaunchKernelGGL(k_score, dim3(32, 1, 16), dim3(256), 0, stream,
                     At1, At2, wt, posbT, kvbD, E, lsumP);
  hipLaunchKernelGGL(k_pv, dim3(8, 2, 16), dim3(256), 0, stream, input1, input2, E, T_p);
  hipLaunchKernelGGL(k_agentv, dim3(NH, 16), dim3(256), 0, stream, T_p, lsumP, Wkt, kv_b, agent_v);
  hipLaunchKernelGGL(k_qattn, dim3(NPOS / 256, NH, 16), dim3(256), 0, stream,
                     guid, qd, agent_v, na_b, ha_b, wa_b, o1s, o2s);
  hipLaunchKernelGGL(k_dwconv, dim3(NPOS / 8, B_, 2), dim3(256), 0, stream,
                     v1, v2, dwcT, o1s, o2s);
  hipLaunchKernelGGL(k_proj_mfma, dim3(32, 2, 16), dim3(256), 0, stream,
                     o1s, o2s, Pwt, proj_b, input1, input2, out1, out2);
}